// Round 8
// baseline (400.813 us; speedup 1.0000x reference)
//
#include <hip/hip_runtime.h>
#include <cstdint>
#include <cstddef>

#define M_DIM 4096
#define K_DIM 4096
#define N_DIM 11008
#define BM 128
#define BN 128
#define BKB 64                        /* K bytes per K-tile */
#define NT (K_DIM / BKB)              /* 64 K-tiles */
#define NTM (M_DIM / BM)              /* 32 */
#define NTN (N_DIM / BN)              /* 86 */
#define SLOT 16384                    /* A 8KB + B 8KB per K-tile */
#define RING 3                        /* 48 KB LDS -> 3 blocks/CU */

typedef int   int4v   __attribute__((ext_vector_type(4)));
typedef float float4v __attribute__((ext_vector_type(4)));

__device__ __forceinline__ void gload_lds16(const void* g, void* l) {
  __builtin_amdgcn_global_load_lds(
      (const __attribute__((address_space(1))) unsigned int*)g,
      (__attribute__((address_space(3))) unsigned int*)l, 16, 0, 0);
}

// ---------------- x quantization: fp32 -> int8 ----------------
__global__ void quant_x_kernel(const float* __restrict__ x,
                               const float* __restrict__ scale_p,
                               const int* __restrict__ off_p,
                               signed char* __restrict__ xq, int total16) {
  const float inv = 1.0f / scale_p[0];
  const float off = (float)off_p[0];
  int tid = blockIdx.x * blockDim.x + threadIdx.x;
  int stride = gridDim.x * blockDim.x;
  const float4v* x4 = (const float4v*)x;
  int4v* out4 = (int4v*)xq;
  for (int i = tid; i < total16; i += stride) {
    int4v o;
#pragma unroll
    for (int j = 0; j < 4; ++j) {
      float4v v = x4[(size_t)i * 4 + j];
      int r = 0;
#pragma unroll
      for (int e = 0; e < 4; ++e) {
        float q = rintf(v[e] * inv) + off;     // round-half-even, matches jnp.round
        q = fminf(fmaxf(q, -128.0f), 127.0f);
        int qi = (int)q;
        r |= (qi & 0xff) << (8 * e);
      }
      o[j] = r;
    }
    out4[i] = o;
  }
}

// ---------------- weight pack: int32 carrier -> int8 ----------------
__global__ void pack_w_kernel(const int* __restrict__ w,
                              signed char* __restrict__ wq, int total16) {
  int tid = blockIdx.x * blockDim.x + threadIdx.x;
  int stride = gridDim.x * blockDim.x;
  const int4v* w4 = (const int4v*)w;
  int4v* out4 = (int4v*)wq;
  for (int i = tid; i < total16; i += stride) {
    int4v o;
#pragma unroll
    for (int j = 0; j < 4; ++j) {
      int4v v = w4[(size_t)i * 4 + j];
      o[j] = (v[0] & 0xff) | ((v[1] & 0xff) << 8) |
             ((v[2] & 0xff) << 16) | ((v[3] & 0xff) << 24);
    }
    out4[i] = o;
  }
}

// ---- int8 GEMM: 128x128 tile, 4 waves x 64x64, ring-3, 3 blocks/CU ----
// A: xq [M][K] int8, B: wq [N][K] int8 (B^T), out fp32 [M][N]
// LDS fragment-packed (0 conflicts, verified R2-R7): frag f = 1 KB, rows
// f*16..+15 (A: f<8, B: f-8), K bytes of the tile; lane l's 16B at
// frag*1024 + l*16 = [16f+(l&15)][(l>>4)*16 ..+16].  Ring of 3 slots.
// Per tile: {STG kt+2; lgkm(0)[stale]; MFMA half1; vmcnt(4)[stale]; barrier;
// RD next-tile operands; MFMA half2} -> all waits hit ops issued >=1 tile ago;
// 3 independent blocks/CU overlap each other's residual stalls.
__global__ __launch_bounds__(256, 3) void gemm_i8_kernel(
    const signed char* __restrict__ A,
    const signed char* __restrict__ B,
    const int* __restrict__ qbias,
    const float* __restrict__ dscale,
    float* __restrict__ out) {
  __shared__ __attribute__((aligned(16))) signed char lds[RING * SLOT];  // 48 KB

  const int tid  = threadIdx.x;
  const int lane = tid & 63;
  const int wv   = tid >> 6;   // 0..3
  const int wr   = wv >> 1;    // 0..1  (M half: 64 rows)
  const int wc   = wv & 1;     // 0..1  (N half: 64 cols)

  // XCD swizzle: 2752 blocks; XCD x owns tm in {4x..4x+3} (A: 4x512KB L2-res),
  // tn-major in time so 4 consecutive blocks share one B-panel.
  int bid = blockIdx.x;
  int s   = bid >> 3;                  // 0..343
  int tm  = 4 * (bid & 7) + (s & 3);   // 0..31
  int tn  = s >> 2;                    // 0..85

  // ---- staging: wave wv stages frags 4wv..4wv+3 (wv<2: A rows, wv>=2: B) ----
  const signed char* pS;
  if (wv < 2)
    pS = A + (size_t)(tm * BM + wv * 64 + (lane & 15)) * K_DIM + (lane >> 4) * 16;
  else
    pS = B + (size_t)(tn * BN + (wv - 2) * 64 + (lane & 15)) * K_DIM + (lane >> 4) * 16;
  const int ldst0 = wv * 4096;         // frag (4wv)*1024

#define STG(KTW, SO) do {                                                     \
    _Pragma("unroll") for (int i = 0; i < 4; ++i)                             \
      gload_lds16(pS + (size_t)i * 16 * K_DIM + (size_t)(KTW) * BKB,          \
                  lds + (SO) + ldst0 + i * 1024); } while (0)

  // ---- ds_read: A frags wr*4+m, B frags 8+wc*4+n (base + lane*16) ----
  const int rdA = (wr * 4) * 1024 + lane * 16;
  const int rdB = (8 + wc * 4) * 1024 + lane * 16;

#define RD(AB, BB, SO) do {                                                   \
    _Pragma("unroll") for (int m = 0; m < 4; ++m)                             \
      AB[m] = *(const int4v*)(lds + (SO) + rdA + m * 1024);                   \
    _Pragma("unroll") for (int n = 0; n < 4; ++n)                             \
      BB[n] = *(const int4v*)(lds + (SO) + rdB + n * 1024); } while (0)

#define MFMA_HALF(AB, BB, M0) do {                                            \
    __builtin_amdgcn_s_setprio(1);                                            \
    _Pragma("unroll") for (int m = 0; m < 2; ++m)                             \
      _Pragma("unroll") for (int n = 0; n < 4; ++n)                           \
        acc[(M0) + m][n] = __builtin_amdgcn_mfma_i32_16x16x64_i8(             \
            AB[(M0) + m], BB[n], acc[(M0) + m][n], 0, 0, 0);                  \
    __builtin_amdgcn_s_setprio(0); } while (0)

  // One tile: compute from (CA,CB) in slot scur, prefetch regs (PA,PB) from snxt,
  // stage tile KTP2 into snx2.
#define TILEBODY(CA, CB, PA, PB, KTP2, SCUR, SNXT, SNX2) do {                 \
    STG((KTP2) & (NT - 1), SNX2);                                             \
    asm volatile("s_waitcnt lgkmcnt(0)" ::: "memory");   /* CA/CB ready */    \
    __builtin_amdgcn_sched_barrier(0);                                        \
    MFMA_HALF(CA, CB, 0);                                                     \
    asm volatile("s_waitcnt vmcnt(4)" ::: "memory");     /* tile kt+1 in */   \
    __builtin_amdgcn_sched_barrier(0);                                        \
    __builtin_amdgcn_s_barrier();                        /* visible to all */ \
    __builtin_amdgcn_sched_barrier(0);                                        \
    RD(PA, PB, SNXT);                                    /* next tile regs */ \
    MFMA_HALF(CA, CB, 2);                                                     \
  } while (0)

  int4v acc[4][4];
#pragma unroll
  for (int i = 0; i < 4; ++i)
#pragma unroll
    for (int j = 0; j < 4; ++j) acc[i][j] = (int4v){0, 0, 0, 0};

  int4v A0[4], B0[4], A1[4], B1[4];

  // ---- prologue ----
  STG(0, 0);
  STG(1, SLOT);
  asm volatile("s_waitcnt vmcnt(4)" ::: "memory");   // tile 0 landed
  __builtin_amdgcn_sched_barrier(0);
  __builtin_amdgcn_s_barrier();
  __builtin_amdgcn_sched_barrier(0);
  RD(A0, B0, 0);                                     // operands for kt=0

  int scur = 0, snxt = SLOT, snx2 = 2 * SLOT;
  for (int t = 0; t < NT / 2; ++t) {
    const int kt = 2 * t;
    TILEBODY(A0, B0, A1, B1, kt + 2, scur, snxt, snx2);
    { int tmp = scur; scur = snxt; snxt = snx2; snx2 = tmp; }
    TILEBODY(A1, B1, A0, B0, kt + 3, scur, snxt, snx2);
    { int tmp = scur; scur = snxt; snxt = snx2; snx2 = tmp; }
  }
  asm volatile("s_waitcnt vmcnt(0) lgkmcnt(0)" ::: "memory");  // drain tail
#undef TILEBODY
#undef MFMA_HALF
#undef RD
#undef STG

  // ---- epilogue: out[m][n] = (acc + qbias[n]) * dscale[n] ----
  const int col = lane & 15;
  const int rb  = (lane >> 4) * 4;
  const int gm0 = tm * BM + wr * 64;
  const int gn0 = tn * BN + wc * 64;
#pragma unroll
  for (int n = 0; n < 4; ++n) {
    int gn = gn0 + n * 16 + col;
    float ds = dscale[gn];
    int qb = qbias[gn];
#pragma unroll
    for (int m = 0; m < 4; ++m) {
      int gm = gm0 + m * 16 + rb;
#pragma unroll
      for (int j = 0; j < 4; ++j)
        out[(size_t)(gm + j) * N_DIM + gn] = (float)(acc[m][n][j] + qb) * ds;
    }
  }
}

extern "C" void kernel_launch(void* const* d_in, const int* in_sizes, int n_in,
                              void* d_out, int out_size, void* d_ws, size_t ws_size,
                              hipStream_t stream) {
  const float* x      = (const float*)d_in[0];
  const int*   w      = (const int*)d_in[1];
  const float* dscale = (const float*)d_in[2];
  const float* iscale = (const float*)d_in[3];
  const int*   ioff   = (const int*)d_in[4];
  const int*   qbias  = (const int*)d_in[5];
  float* out = (float*)d_out;

  const size_t xq_bytes = (size_t)M_DIM * K_DIM;        // 16 MB
  const size_t wq_bytes = (size_t)N_DIM * K_DIM;        // 45 MB
  if (ws_size < xq_bytes + wq_bytes) return;

  signed char* xq = (signed char*)d_ws;
  signed char* wq = (signed char*)d_ws + xq_bytes;

  quant_x_kernel<<<2048, 256, 0, stream>>>(x, iscale, ioff, xq, M_DIM * K_DIM / 16);
  pack_w_kernel<<<2048, 256, 0, stream>>>(w, wq, N_DIM * K_DIM / 16);
  gemm_i8_kernel<<<NTM * NTN, 256, 0, stream>>>(xq, wq, qbias, dscale, out);
}

// Round 9
// 252.759 us; speedup vs baseline: 1.5858x; 1.5858x over previous
//
#include <hip/hip_runtime.h>
#include <cstdint>
#include <cstddef>

#define M_DIM 4096
#define K_DIM 4096
#define N_DIM 11008
#define BM 256
#define BN 256
#define BKB 128                       /* K bytes per K-step (2 MFMA k-slices) */
#define NT (K_DIM / BKB)              /* 32 K-steps */
#define NTM (M_DIM / BM)              /* 16 */
#define NTN (N_DIM / BN)              /* 43 */
#define SLOT_BYTES 65536              /* A 32KB + B 32KB */
#define B_OFF 32768

typedef int   int4v   __attribute__((ext_vector_type(4)));
typedef float float4v __attribute__((ext_vector_type(4)));

__device__ __forceinline__ void gload_lds16(const void* g, void* l) {
  __builtin_amdgcn_global_load_lds(
      (const __attribute__((address_space(1))) unsigned int*)g,
      (__attribute__((address_space(3))) unsigned int*)l, 16, 0, 0);
}

// ---------------- x quantization: fp32 -> int8 ----------------
__global__ void quant_x_kernel(const float* __restrict__ x,
                               const float* __restrict__ scale_p,
                               const int* __restrict__ off_p,
                               signed char* __restrict__ xq, int total16) {
  const float inv = 1.0f / scale_p[0];
  const float off = (float)off_p[0];
  int tid = blockIdx.x * blockDim.x + threadIdx.x;
  int stride = gridDim.x * blockDim.x;
  const float4v* x4 = (const float4v*)x;
  int4v* out4 = (int4v*)xq;
  for (int i = tid; i < total16; i += stride) {
    int4v o;
#pragma unroll
    for (int j = 0; j < 4; ++j) {
      float4v v = x4[(size_t)i * 4 + j];
      int r = 0;
#pragma unroll
      for (int e = 0; e < 4; ++e) {
        float q = rintf(v[e] * inv) + off;     // round-half-even, matches jnp.round
        q = fminf(fmaxf(q, -128.0f), 127.0f);
        int qi = (int)q;
        r |= (qi & 0xff) << (8 * e);
      }
      o[j] = r;
    }
    out4[i] = o;
  }
}

// ---------------- weight pack: int32 carrier -> int8 ----------------
__global__ void pack_w_kernel(const int* __restrict__ w,
                              signed char* __restrict__ wq, int total16) {
  int tid = blockIdx.x * blockDim.x + threadIdx.x;
  int stride = gridDim.x * blockDim.x;
  const int4v* w4 = (const int4v*)w;
  int4v* out4 = (int4v*)wq;
  for (int i = tid; i < total16; i += stride) {
    int4v o;
#pragma unroll
    for (int j = 0; j < 4; ++j) {
      int4v v = w4[(size_t)i * 4 + j];
      o[j] = (v[0] & 0xff) | ((v[1] & 0xff) << 8) |
             ((v[2] & 0xff) << 16) | ((v[3] & 0xff) << 24);
    }
    out4[i] = o;
  }
}

// -------- int8 GEMM: faithful m201 port.  256x256, 8 waves (2Mx4N), ---------
// -------- row-major swizzled LDS, 4 phases/K-step, counted vmcnt(6). ---------
// LDS per slot: A rows [0,256) at R*128, B at B_OFF + R*128; 128-B rows.
// Swizzle (involution): LDS[R*128 + c] holds tile[R][c ^ ((R&7)<<4)].
// DMA dest stays LINEAR; the global SOURCE is pre-swizzled per-lane (m173).
// Phase p reads A-frags 2p,2p+1 (rows p*32..+31 of each 128-half) + (P0) all B.
// Staging regions match the read-free schedule => race-free by barrier order.
__global__ __launch_bounds__(512, 2) void gemm_i8_kernel(
    const signed char* __restrict__ A,
    const signed char* __restrict__ B,
    const int* __restrict__ qbias,
    const float* __restrict__ dscale,
    float* __restrict__ out) {
  __shared__ __attribute__((aligned(16))) signed char lds[2 * SLOT_BYTES];  // 128 KB

  const int tid  = threadIdx.x;
  const int lane = tid & 63;
  const int wv   = tid >> 6;   // 0..7
  const int wr   = wv >> 2;    // 0..1  (M half: 128 rows)
  const int wc   = wv & 3;     // 0..3  (N quarter: 64 cols)

  // XCD swizzle (R6-style, best FETCH): xcd owns tm pair {2x,2x+1}; tn slow.
  int bid = blockIdx.x;
  int s   = bid >> 3;                 // 0..85
  int tm  = 2 * (bid & 7) + (s & 1);  // 0..15
  int tn  = s >> 1;                   // 0..42

  // ---- staging constants (pre-swizzled global source, linear LDS dest) ----
  const int csw  = (((tid & 7) ^ ((tid >> 3) & 7)) << 4);  // swizzled col chunk
  // A: rows {0..31} u {128..159} (+ p*32); per-thread row:
  const int rA   = ((tid >> 8) << 7) + ((tid & 255) >> 3);
  const signed char* sAp = A + (size_t)(tm * BM + rA) * K_DIM + csw;
  const int dA0  = ((tid >> 8) << 14) + (((tid >> 6) & 3) << 10) + ((tid & 63) << 4);
  // B: rows q*64 + tid>>3:
  const int rB   = tid >> 3;
  const signed char* sBp = B + (size_t)(tn * BN + rB) * K_DIM + csw;
  const int dB0  = B_OFF + (tid << 4);

  // STGP(step, x): stage A phase-region x and B region x of `step`.
#define STGP(STEP, X) do {                                                    \
    int st_ = (STEP) & (NT - 1);                                              \
    int sl_ = (st_ & 1) * SLOT_BYTES;                                         \
    gload_lds16(sAp + (size_t)(X) * 32 * K_DIM + (size_t)st_ * BKB,           \
                lds + sl_ + dA0 + (X) * 4096);                                \
    gload_lds16(sBp + (size_t)(X) * 64 * K_DIM + (size_t)st_ * BKB,           \
                lds + sl_ + dB0 + (X) * 8192); } while (0)

  // ---- swizzled ds_read constants ----
  const int sx  = (lane & 7) << 4;
  const int q16 = ((lane >> 4) & 3) << 4;
  const int ck0 = q16 ^ sx;             // col bytes, ks=0
  const int ck1 = (64 + q16) ^ sx;      // col bytes, ks=1
  const int rbA = (wr * 128 + (lane & 15)) * 128;           // + frag*2048
  const int rbB = B_OFF + (wc * 64 + (lane & 15)) * 128;    // + ni*2048

#define RDA(buf, SB, P) do {                                                  \
    _Pragma("unroll") for (int d = 0; d < 2; ++d) {                           \
      buf[d][0] = *(const int4v*)(lds + (SB) + rbA + (2*(P)+d)*2048 + ck0);   \
      buf[d][1] = *(const int4v*)(lds + (SB) + rbA + (2*(P)+d)*2048 + ck1);   \
    } } while (0)
#define RDB(SB) do {                                                          \
    _Pragma("unroll") for (int ni = 0; ni < 4; ++ni) {                        \
      bfr[ni][0] = *(const int4v*)(lds + (SB) + rbB + ni*2048 + ck0);         \
      bfr[ni][1] = *(const int4v*)(lds + (SB) + rbB + ni*2048 + ck1);         \
    } } while (0)
#define MM(af, P) do {                                                        \
    __builtin_amdgcn_s_setprio(1);                                            \
    _Pragma("unroll") for (int d = 0; d < 2; ++d)                             \
      _Pragma("unroll") for (int ni = 0; ni < 4; ++ni)                        \
        _Pragma("unroll") for (int ks = 0; ks < 2; ++ks)                      \
          acc[2*(P)+d][ni] = __builtin_amdgcn_mfma_i32_16x16x64_i8(           \
              af[d][ks], bfr[ni][ks], acc[2*(P)+d][ni], 0, 0, 0);             \
    __builtin_amdgcn_s_setprio(0); } while (0)

  int4v acc[8][4];
#pragma unroll
  for (int i = 0; i < 8; ++i)
#pragma unroll
    for (int j = 0; j < 4; ++j) acc[i][j] = (int4v){0, 0, 0, 0};

  int4v af0[2][2], af1[2][2], bfr[4][2];

  // ---- prologue: step0 full (8), step1 regions 0-2 (6); wait step0 ----
  STGP(0, 0); STGP(0, 1); STGP(0, 2); STGP(0, 3);
  STGP(1, 0); STGP(1, 1); STGP(1, 2);
  asm volatile("s_waitcnt vmcnt(6)" ::: "memory");
  __builtin_amdgcn_s_barrier();

  for (int t = 0; t < NT; ++t) {
    const int sb = (t & 1) * SLOT_BYTES;
    // P0: B(all) + A frags 0,1 ; finish staging step t+1
    RDB(sb); RDA(af0, sb, 0);
    STGP(t + 1, 3);
    asm volatile("s_waitcnt lgkmcnt(8)" ::: "memory");
    __builtin_amdgcn_s_barrier();
    asm volatile("s_waitcnt lgkmcnt(0)" ::: "memory");
    MM(af0, 0);
    __builtin_amdgcn_s_barrier();
    // P1
    RDA(af1, sb, 1);
    STGP(t + 2, 0);
    __builtin_amdgcn_s_barrier();
    asm volatile("s_waitcnt lgkmcnt(0)" ::: "memory");
    MM(af1, 1);
    __builtin_amdgcn_s_barrier();
    // P2
    RDA(af0, sb, 2);
    STGP(t + 2, 1);
    __builtin_amdgcn_s_barrier();
    asm volatile("s_waitcnt lgkmcnt(0)" ::: "memory");
    MM(af0, 2);
    __builtin_amdgcn_s_barrier();
    // P3  (counted vmcnt: step t+1 fully landed; 6 newer loads in flight)
    RDA(af1, sb, 3);
    STGP(t + 2, 2);
    __builtin_amdgcn_s_barrier();
    asm volatile("s_waitcnt lgkmcnt(0)" ::: "memory");
    MM(af1, 3);
    asm volatile("s_waitcnt vmcnt(6)" ::: "memory");
    __builtin_amdgcn_s_barrier();
  }
  asm volatile("s_waitcnt vmcnt(0) lgkmcnt(0)" ::: "memory");  // drain tail
#undef MM
#undef RDB
#undef RDA
#undef STGP

  // ---- epilogue: out[m][n] = (acc + qbias[n]) * dscale[n] ----
  const int col = lane & 15;
  const int rb  = (lane >> 4) * 4;
  const int gm0 = tm * BM + wr * 128;
  const int gn0 = tn * BN + wc * 64;
#pragma unroll
  for (int ni = 0; ni < 4; ++ni) {
    int gn = gn0 + ni * 16 + col;
    float ds = dscale[gn];
    int qb = qbias[gn];
#pragma unroll
    for (int mi = 0; mi < 8; ++mi) {
      int gm = gm0 + mi * 16 + rb;
#pragma unroll
      for (int j = 0; j < 4; ++j)
        out[(size_t)(gm + j) * N_DIM + gn] = (float)(acc[mi][ni][j] + qb) * ds;
    }
  }
}

extern "C" void kernel_launch(void* const* d_in, const int* in_sizes, int n_in,
                              void* d_out, int out_size, void* d_ws, size_t ws_size,
                              hipStream_t stream) {
  const float* x      = (const float*)d_in[0];
  const int*   w      = (const int*)d_in[1];
  const float* dscale = (const float*)d_in[2];
  const float* iscale = (const float*)d_in[3];
  const int*   ioff   = (const int*)d_in[4];
  const int*   qbias  = (const int*)d_in[5];
  float* out = (float*)d_out;

  const size_t xq_bytes = (size_t)M_DIM * K_DIM;        // 16 MB
  const size_t wq_bytes = (size_t)N_DIM * K_DIM;        // 45 MB
  if (ws_size < xq_bytes + wq_bytes) return;

  signed char* xq = (signed char*)d_ws;
  signed char* wq = (signed char*)d_ws + xq_bytes;

  quant_x_kernel<<<2048, 256, 0, stream>>>(x, iscale, ioff, xq, M_DIM * K_DIM / 16);
  pack_w_kernel<<<2048, 256, 0, stream>>>(w, wq, N_DIM * K_DIM / 16);
  gemm_i8_kernel<<<NTM * NTN, 512, 0, stream>>>(xq, wq, qbias, dscale, out);
}